// Round 2
// baseline (458.888 us; speedup 1.0000x reference)
//
#include <hip/hip_runtime.h>
#include <hip/hip_bf16.h>

#define E_TOT 300000

typedef float  f32x4  __attribute__((ext_vector_type(4)));
typedef __bf16 bf16x8 __attribute__((ext_vector_type(8)));

__device__ __forceinline__ unsigned short f2bf(float f) {
    union { float f; unsigned int u; } v; v.f = f;
    return (unsigned short)((v.u + 0x7FFFu + ((v.u >> 16) & 1u)) >> 16);
}

__device__ __forceinline__ unsigned int packbf2(float x, float y) {
    __hip_bfloat162 h = __float22bfloat162_rn(make_float2(x, y));
    union { __hip_bfloat162 h; unsigned int u; } cv; cv.h = h;
    return cv.u;
}

// Repack weights into fragment-linear bf16 so a wave's B-fragment load is one
// coalesced 1KB global_load_dwordx4 (lane*16B contiguous):
//   W1q[(((c*4+w)*4+nt)*2+ks)*512 + lane*8 + j] = W1[k][n]
//     k = c*64+ks*32+quad*8+j,  n = w*64+nt*16+l16   (c<6, w<4, nt<4, ks<2)
//   W2q[((c2*2+ks)*8+nt)*512 + lane*8 + j] = W2[k][n]
//     k = c2*64+ks*32+quad*8+j, n = nt*16+l16        (c2<4, ks<2, nt<8)
__global__ void prep_weights(const float* __restrict__ W1,
                             const float* __restrict__ W2,
                             unsigned short* __restrict__ W1q,
                             unsigned short* __restrict__ W2q) {
    int t = blockIdx.x * 256 + threadIdx.x;
    if (t < 98304) {
        int j    = t & 7;
        int lane = (t >> 3) & 63;
        int ks   = (t >> 9) & 1;
        int nt   = (t >> 10) & 3;
        int w    = (t >> 12) & 3;
        int c    = t >> 14;
        int quad = lane >> 4, l16 = lane & 15;
        int k = c * 64 + ks * 32 + quad * 8 + j;
        int n = w * 64 + nt * 16 + l16;
        W1q[t] = f2bf(W1[k * 256 + n]);
    } else {
        int t2   = t - 98304;
        int j    = t2 & 7;
        int lane = (t2 >> 3) & 63;
        int nt   = (t2 >> 9) & 7;
        int ks   = (t2 >> 12) & 1;
        int c2   = t2 >> 13;
        int quad = lane >> 4, l16 = lane & 15;
        int k = c2 * 64 + ks * 32 + quad * 8 + j;
        int n = nt * 16 + l16;
        W2q[t2] = f2bf(W2[k * 128 + n]);
    }
}

__global__ __launch_bounds__(256, 4) void edge_mlp(
    const float* __restrict__ node_attr,
    const float* __restrict__ edge_attr,
    const int*   __restrict__ eidx,
    const unsigned short* __restrict__ W1q,
    const unsigned short* __restrict__ W2q,
    const float* __restrict__ b1,
    const float* __restrict__ b2,
    const float* __restrict__ ln_g,
    const float* __restrict__ ln_b,
    float* __restrict__ out)
{
    // 33792B unioned: layer1 {Xc0[64][72] @0, Xc1[64][72] @4608 (x2 dbuf)}
    //                 layer2 {hbuf[64][264] @0}
    __shared__ __align__(16) unsigned short smem[16896];
    __shared__ int sIdx[64], rIdx[64];
    unsigned short* const Xc0  = smem;
    unsigned short* const Xc1  = smem + 4608;
    unsigned short* const hbuf = smem;

    const int tid  = threadIdx.x;
    const int wid  = tid >> 6;
    const int lane = tid & 63;
    const int quad = lane >> 4;
    const int l16  = lane & 15;
    const int eb   = blockIdx.x * 64;
    const int grow = tid >> 4;   // base gather row (0..15)
    const int q4   = tid & 15;   // float4 unit within row

    if (tid < 128) {
        int r = tid & 63;
        int e = eb + r; if (e >= E_TOT) e = E_TOT - 1;
        if (tid < 64) sIdx[r] = eidx[e];
        else          rIdx[r] = eidx[E_TOT + e];
    }

    float b1v[4];
    #pragma unroll
    for (int nt = 0; nt < 4; ++nt) b1v[nt] = b1[(wid << 6) + (nt << 4) + l16];

    f32x4 acc[4][4];
    #pragma unroll
    for (int i = 0; i < 4; ++i)
        #pragma unroll
        for (int j = 0; j < 4; ++j)
            acc[i][j] = (f32x4){0.f, 0.f, 0.f, 0.f};

    __syncthreads();

    auto gather = [&](int cc, float4* v) {
        const int coloff = (cc & 1) << 6;
        #pragma unroll
        for (int i = 0; i < 4; ++i) {
            int row = (i << 4) + grow;
            const float* src;
            if (cc < 2)      src = node_attr + (size_t)sIdx[row] * 128;
            else if (cc < 4) src = node_attr + (size_t)rIdx[row] * 128;
            else {
                int e = eb + row; if (e >= E_TOT) e = E_TOT - 1;
                src = edge_attr + (size_t)e * 128;
            }
            v[i] = *(const float4*)(src + coloff + (q4 << 2));
        }
    };
    auto store_x = [&](unsigned short* xb, const float4* v) {
        #pragma unroll
        for (int i = 0; i < 4; ++i) {
            int row = (i << 4) + grow;
            union { unsigned int u[2]; ushort4 s; } p;
            p.u[0] = packbf2(v[i].x, v[i].y);
            p.u[1] = packbf2(v[i].z, v[i].w);
            *(ushort4*)(xb + row * 72 + (q4 << 2)) = p.s;
        }
    };

    {   // prologue: chunk 0 into buf0
        float4 v[4];
        gather(0, v);
        store_x(Xc0, v);
    }
    __syncthreads();

    // ---------- Layer 1: X[64x384] @ W1[384x256], double-buffered X ----------
    #pragma unroll 1
    for (int c = 0; c < 6; ++c) {
        const unsigned short* xb = (c & 1) ? Xc1 : Xc0;
        unsigned short*       xn = (c & 1) ? Xc0 : Xc1;
        float4 v[4];
        if (c < 5) gather(c + 1, v);        // overlap with MFMAs below
        #pragma unroll
        for (int ks = 0; ks < 2; ++ks) {
            bf16x8 a[4];
            #pragma unroll
            for (int mt = 0; mt < 4; ++mt)
                a[mt] = *(const bf16x8*)(xb + ((mt << 4) + l16) * 72 + (ks << 5) + (quad << 3));
            #pragma unroll
            for (int nt = 0; nt < 4; ++nt) {
                bf16x8 b = *(const bf16x8*)(W1q
                    + (((((c << 2) + wid) << 2) + nt) * 2 + ks) * 512 + (lane << 3));
                #pragma unroll
                for (int mt = 0; mt < 4; ++mt)
                    acc[mt][nt] = __builtin_amdgcn_mfma_f32_16x16x32_bf16(a[mt], b, acc[mt][nt], 0, 0, 0);
            }
        }
        if (c < 5) store_x(xn, v);
        __syncthreads();                    // one barrier per chunk
    }

    // ---------- bias + ReLU -> hbuf (Xc reads all done at last barrier) ----------
    #pragma unroll
    for (int mt = 0; mt < 4; ++mt)
        #pragma unroll
        for (int nt = 0; nt < 4; ++nt)
            #pragma unroll
            for (int r = 0; r < 4; ++r) {
                int row = (mt << 4) + (quad << 2) + r;
                int col = (wid << 6) + (nt << 4) + l16;
                float hv = acc[mt][nt][r] + b1v[nt];
                hbuf[row * 264 + col] = f2bf(hv > 0.f ? hv : 0.f);
            }
    __syncthreads();

    // ---------- Layer 2: h[64x256] @ W2[256x128], B direct from L2 ----------
    f32x4 acc2[8];
    #pragma unroll
    for (int nt = 0; nt < 8; ++nt) acc2[nt] = (f32x4){0.f, 0.f, 0.f, 0.f};

    #pragma unroll 1
    for (int c2 = 0; c2 < 4; ++c2) {
        #pragma unroll
        for (int ks = 0; ks < 2; ++ks) {
            bf16x8 a = *(const bf16x8*)(hbuf + ((wid << 4) + l16) * 264 + (c2 << 6) + (ks << 5) + (quad << 3));
            #pragma unroll
            for (int nt = 0; nt < 8; ++nt) {
                bf16x8 b = *(const bf16x8*)(W2q
                    + ((((c2 << 1) + ks) << 3) + nt) * 512 + (lane << 3));
                acc2[nt] = __builtin_amdgcn_mfma_f32_16x16x32_bf16(a, b, acc2[nt], 0, 0, 0);
            }
        }
    }

    // ---------- bias + LayerNorm (in-register, 16-lane shuffle) ----------
    float b2v[8], gv[8], bev[8];
    #pragma unroll
    for (int nt = 0; nt < 8; ++nt) {
        int n = (nt << 4) + l16;
        b2v[nt] = b2[n]; gv[nt] = ln_g[n]; bev[nt] = ln_b[n];
    }
    #pragma unroll
    for (int r = 0; r < 4; ++r) {
        int e = eb + (wid << 4) + (quad << 2) + r;
        float x[8];
        float s = 0.f, s2 = 0.f;
        #pragma unroll
        for (int nt = 0; nt < 8; ++nt) {
            x[nt] = acc2[nt][r] + b2v[nt];
            s += x[nt]; s2 += x[nt] * x[nt];
        }
        #pragma unroll
        for (int m = 1; m < 16; m <<= 1) {
            s  += __shfl_xor(s, m, 64);
            s2 += __shfl_xor(s2, m, 64);
        }
        const float mu  = s * (1.f / 128.f);
        const float var = s2 * (1.f / 128.f) - mu * mu;
        const float rs  = rsqrtf(var + 1e-5f);
        if (e < E_TOT) {
            float* orow = out + (size_t)e * 128;
            #pragma unroll
            for (int nt = 0; nt < 8; ++nt)
                orow[(nt << 4) + l16] = (x[nt] - mu) * rs * gv[nt] + bev[nt];
        }
    }
}

extern "C" void kernel_launch(void* const* d_in, const int* in_sizes, int n_in,
                              void* d_out, int out_size, void* d_ws, size_t ws_size,
                              hipStream_t stream) {
    const float* node_attr = (const float*)d_in[0];
    const float* edge_attr = (const float*)d_in[1];
    const int*   eidx      = (const int*)d_in[2];
    const float* W1        = (const float*)d_in[3];
    const float* b1        = (const float*)d_in[4];
    const float* W2        = (const float*)d_in[5];
    const float* b2        = (const float*)d_in[6];
    const float* ln_g      = (const float*)d_in[7];
    const float* ln_b      = (const float*)d_in[8];

    unsigned short* W1q = (unsigned short*)d_ws;   // 98304 bf16
    unsigned short* W2q = W1q + 98304;             // 32768 bf16

    prep_weights<<<512, 256, 0, stream>>>(W1, W2, W1q, W2q);

    const int nblocks = (E_TOT + 63) / 64;         // 4688
    edge_mlp<<<nblocks, 256, 0, stream>>>(node_attr, edge_attr, eidx,
                                          W1q, W2q, b1, b2, ln_g, ln_b,
                                          (float*)d_out);
}